// Round 11
// baseline (204.458 us; speedup 1.0000x reference)
//
#include <hip/hip_runtime.h>
#include <hip/hip_bf16.h>
#include <math.h>

#define HPIX 128
#define WPIX 128
#define NPIX (HPIX*WPIX)   // 16384
#define CCH 64
#define P2 256             // number of windows (16x16)
#define HWIN 64            // pixels per window (8x8)
#define LNS 36             // LDS row stride (floats), 144B, 16B-aligned

__device__ __forceinline__ float waveReduceSum(float v){
  #pragma unroll
  for (int m = 32; m >= 1; m >>= 1) v += __shfl_xor(v, m);
  return v;
}

__device__ __forceinline__ float gelu_exact(float h){
  return 0.5f*h*(1.f + erff(h*0.70710678118654752f));
}

// K1: x1(NHWC,f32) = x + dwconv3x3(x,pos_w,pos_b). LDS-staged rows. (round-9)
__global__ void k1_posconv(const float* __restrict__ x, const float* __restrict__ pw,
                           const float* __restrict__ pb, float* __restrict__ x1){
  __shared__ float tile[4][3][72];
  __shared__ float lds[4][64];
  int tid = threadIdx.x;
  int pl = tid & 63, cl = tid >> 6;
  int pix0 = (blockIdx.x & 255) * 64;
  int cg   = (blockIdx.x >> 8);
  int c = cg*4 + cl;
  int y  = pix0 >> 7;
  int xb = pix0 & 127;
  const float* xc = x + c*NPIX;
  for (int t = pl; t < 3*66; t += 64){
    int r = t / 66, ccol = t - r*66;
    int yy = y - 1 + r, xxr = xb - 1 + ccol;
    float v = 0.f;
    if ((unsigned)yy < (unsigned)HPIX && (unsigned)xxr < (unsigned)WPIX)
      v = xc[yy*WPIX + xxr];
    tile[cl][r][ccol] = v;
  }
  float wreg[9];
  #pragma unroll
  for (int t=0;t<9;t++) wreg[t] = pw[c*9+t];
  float bias = pb[c];
  __syncthreads();
  float acc = bias;
  #pragma unroll
  for (int dy=0;dy<3;dy++)
    #pragma unroll
    for (int dx=0;dx<3;dx++)
      acc += wreg[dy*3+dx] * tile[cl][dy][pl+dx];
  lds[cl][pl] = tile[cl][1][pl+1] + acc;
  __syncthreads();
  int pp = tid >> 2, cc = tid & 3;
  x1[(pix0+pp)*CCH + cg*4 + cc] = lds[cc][pp];
}

// K2: LN + qkv. 32 px/block, 256 thr, grid 512. (round-10 proven)
__global__ void k2_ln_qkv(const float* __restrict__ x1,
                          const float* __restrict__ g, const float* __restrict__ bb,
                          const float* __restrict__ qw, const float* __restrict__ qb,
                          float* __restrict__ qkv){
  __shared__ __align__(16) float lnT[64][LNS];
  int tid = threadIdx.x, w = tid >> 6, lane = tid & 63;
  int pix0 = blockIdx.x * 32;
  #pragma unroll
  for (int i=0; i<8; i++){
    int pl = w*8 + i, pix = pix0 + pl;
    float v = x1[pix*CCH + lane];
    float mean = waveReduceSum(v) * (1.f/64.f);
    float d = v - mean;
    float var = waveReduceSum(d*d) * (1.f/64.f);
    lnT[lane][pl] = d * rsqrtf(var + 1e-6f) * g[lane] + bb[lane];
  }
  __syncthreads();
  int p0 = (tid & 7) * 4;
  int cg = tid >> 3;
  int j0 = cg * 6;
  float acc[4][6];
  #pragma unroll
  for (int i=0;i<4;i++)
    #pragma unroll
    for (int j=0;j<6;j++) acc[i][j] = qb[j0+j];
  for (int k0=0; k0<64; k0+=2){
    float4 a0 = *(const float4*)&lnT[k0][p0];
    float4 a1 = *(const float4*)&lnT[k0+1][p0];
    const float* wr0 = qw + k0*192 + j0;
    const float* wr1 = wr0 + 192;
    float2 u00 = *(const float2*)(wr0);
    float2 u01 = *(const float2*)(wr0+2);
    float2 u02 = *(const float2*)(wr0+4);
    float2 u10 = *(const float2*)(wr1);
    float2 u11 = *(const float2*)(wr1+2);
    float2 u12 = *(const float2*)(wr1+4);
    float a0v[4] = {a0.x,a0.y,a0.z,a0.w};
    float a1v[4] = {a1.x,a1.y,a1.z,a1.w};
    #pragma unroll
    for (int i=0;i<4;i++){
      acc[i][0]+=a0v[i]*u00.x; acc[i][1]+=a0v[i]*u00.y;
      acc[i][2]+=a0v[i]*u01.x; acc[i][3]+=a0v[i]*u01.y;
      acc[i][4]+=a0v[i]*u02.x; acc[i][5]+=a0v[i]*u02.y;
    }
    #pragma unroll
    for (int i=0;i<4;i++){
      acc[i][0]+=a1v[i]*u10.x; acc[i][1]+=a1v[i]*u10.y;
      acc[i][2]+=a1v[i]*u11.x; acc[i][3]+=a1v[i]*u11.y;
      acc[i][4]+=a1v[i]*u12.x; acc[i][5]+=a1v[i]*u12.y;
    }
  }
  int y = pix0 >> 7;
  int pb_row = (y>>3)*16, rrow = (y&7)<<3, xbase = pix0 & 127;
  #pragma unroll
  for (int i=0;i<4;i++){
    int xx = xbase + p0 + i;
    int p = pb_row + (xx>>3);
    int r = rrow + (xx&7);
    float* o = qkv + (p*HWIN + r)*192 + j0;
    *(float2*)(o)     = make_float2(acc[i][0], acc[i][1]);
    *(float2*)(o + 2) = make_float2(acc[i][2], acc[i][3]);
    *(float2*)(o + 4) = make_float2(acc[i][4], acc[i][5]);
  }
}

// K3: per-window means; kwin stored TRANSPOSED [c][p].
__global__ void k3_winmean(const float* __restrict__ qkv,
                           float* __restrict__ qwin, float* __restrict__ kwinT){
  int p = blockIdx.x;
  int tid = threadIdx.x, rq = tid >> 6, c = tid & 63;
  float sq = 0.f, sk = 0.f;
  for (int r = rq*16; r < rq*16+16; r++){
    const float* row = qkv + (p*HWIN + r)*192;
    sq += row[c];
    sk += row[64 + c];
  }
  __shared__ float s1[4][64], s2[4][64];
  s1[rq][c] = sq; s2[rq][c] = sk;
  __syncthreads();
  if (tid < 64){
    qwin[p*64 + c]   = (s1[0][c]+s1[1][c]+s1[2][c]+s1[3][c])*(1.f/64.f);
    kwinT[c*P2 + p]  = (s2[0][c]+s2[1][c]+s2[2][c]+s2[3][c])*(1.f/64.f);
  }
}

// K4: logits + top-4 (desc, ties -> lowest index).
__global__ void k4_topk(const float* __restrict__ qwin, const float* __restrict__ kwinT,
                        int* __restrict__ idx){
  int p = blockIdx.x, t = threadIdx.x;
  int w = t >> 6, lane = t & 63;
  __shared__ float qs[64];
  __shared__ float lg[P2];
  __shared__ float wv[4]; __shared__ int wi[4];
  if (t < 64) qs[t] = qwin[p*64 + t];
  __syncthreads();
  float acc = 0.f;
  #pragma unroll 8
  for (int c=0; c<64; c++) acc += qs[c] * kwinT[c*P2 + t];
  lg[t] = acc;
  __syncthreads();
  for (int j=0; j<4; j++){
    float v = lg[t]; int i = t;
    #pragma unroll
    for (int m=32; m>=1; m>>=1){
      float ov = __shfl_xor(v, m); int oi = __shfl_xor(i, m);
      if (ov > v || (ov == v && oi < i)){ v = ov; i = oi; }
    }
    if (lane == 0){ wv[w] = v; wi[w] = i; }
    __syncthreads();
    if (t == 0){
      float bv = wv[0]; int bi = wi[0];
      #pragma unroll
      for (int u=1; u<4; u++)
        if (wv[u] > bv || (wv[u] == bv && wi[u] < bi)){ bv = wv[u]; bi = wi[u]; }
      idx[p*4 + j] = bi;
      lg[bi] = -1e30f;
    }
    __syncthreads();
  }
}

// K5: attention (window p, head n). 4 waves split 256 keys; distributed merge;
// ps overlays dead Ks/Vs region. grid 2048, block 256. (round-9)
__global__ void k5_attn(const float* __restrict__ qkv, const int* __restrict__ idx,
                        float* __restrict__ attnout){
  int p = blockIdx.x >> 3, n = blockIdx.x & 7;
  int tid = threadIdx.x, w = tid >> 6, lane = tid & 63;
  __shared__ float Ks[256][8];
  __shared__ float Vs[256][8];
  __shared__ int wsel[4];
  __shared__ float ps_tail[256];
  (void)ps_tail;
  float* psbuf = &Ks[0][0];
  if (tid < 4) wsel[tid] = idx[p*4 + tid];
  __syncthreads();
  int cb = n*8;
  for (int u = tid; u < 512; u += 256){
    int k = u >> 1, h = u & 1;
    const float* row = qkv + (wsel[k>>6]*HWIN + (k&63))*192;
    *(float4*)&Ks[k][h*4] = *(const float4*)(row + 64  + cb + h*4);
    *(float4*)&Vs[k][h*4] = *(const float4*)(row + 128 + cb + h*4);
  }
  __syncthreads();
  const float* qrow = qkv + (p*HWIN + lane)*192 + cb;
  float4 q0 = *(const float4*)(qrow);
  float4 q1 = *(const float4*)(qrow + 4);
  float q[8] = {q0.x*0.125f, q0.y*0.125f, q0.z*0.125f, q0.w*0.125f,
                q1.x*0.125f, q1.y*0.125f, q1.z*0.125f, q1.w*0.125f};
  float l = 0.f, acc[8];
  #pragma unroll
  for (int d=0; d<8; d++) acc[d] = 0.f;
  #pragma unroll 4
  for (int k = w*64; k < w*64+64; k++){
    float4 ka = *(float4*)&Ks[k][0];
    float4 kb = *(float4*)&Ks[k][4];
    float s = q[0]*ka.x + q[1]*ka.y + q[2]*ka.z + q[3]*ka.w
            + q[4]*kb.x + q[5]*kb.y + q[6]*kb.z + q[7]*kb.w;
    float e = __expf(s);
    l += e;
    float4 va = *(float4*)&Vs[k][0];
    float4 vb = *(float4*)&Vs[k][4];
    acc[0]+=e*va.x; acc[1]+=e*va.y; acc[2]+=e*va.z; acc[3]+=e*va.w;
    acc[4]+=e*vb.x; acc[5]+=e*vb.y; acc[6]+=e*vb.z; acc[7]+=e*vb.w;
  }
  __syncthreads();
  float* myp = psbuf + (w*64 + lane)*9;
  #pragma unroll
  for (int d=0; d<8; d++) myp[d] = acc[d];
  myp[8] = l;
  __syncthreads();
  {
    int qi = (w << 4) + (lane & 15);
    int d0 = (lane >> 4) * 2;
    float L = 0.f, o0 = 0.f, o1 = 0.f;
    #pragma unroll
    for (int u=0; u<4; u++){
      const float* pp2 = psbuf + (u*64 + qi)*9;
      L  += pp2[8];
      o0 += pp2[d0];
      o1 += pp2[d0+1];
    }
    float inv = 1.f / L;
    int yy = (p>>4)*8 + (qi>>3), xx = (p&15)*8 + (qi&7);
    float* orow = attnout + (yy*WPIX + xx)*CCH + cb + d0;
    *(float2*)orow = make_float2(o0*inv, o1*inv);
  }
}

// K67: fused lepe+wo+LN+MLP. 32 px/block, grid 512, BLOCK 512 (8 waves ->
// 4 waves/SIMD at 2 blocks/CU, 2x round-10). Same phase structure; per-thread
// tiles halved; fc2 split 4-way in K and 2-way in cols across the 8 waves.
__global__ void __launch_bounds__(512)
k67_lepe_wo_mlp(const float* __restrict__ attnout,
                const float* __restrict__ qkv,
                const float* __restrict__ lw, const float* __restrict__ lb,
                const float* __restrict__ ww, const float* __restrict__ wb,
                const float* __restrict__ x1,
                const float* __restrict__ g, const float* __restrict__ bb,
                const float* __restrict__ w1, const float* __restrict__ b1,
                const float* __restrict__ w2, const float* __restrict__ b2,
                float* __restrict__ out){
  __shared__ __align__(16) float smem[13824];            // 55.3 KB
  float* x2T  = smem;                                    // [64][36]
  float* lnT  = smem + 2304;                             // [64][36]
  float* hidT = smem + 4608;                             // [256][36]
  float* tT   = hidT;                                    // alias (dead before D)
  float* red  = hidT;                                    // alias (after E)
  int tid = threadIdx.x, w = tid >> 6, lane = tid & 63;
  int pix0 = blockIdx.x * 32;

  // Phase A: lepe (lane = channel; wave w -> pixels w*4..w*4+3)
  #pragma unroll
  for (int i=0; i<4; i++){
    int pl = w*4 + i, pix = pix0 + pl;
    int y = pix >> 7, xx = pix & 127;
    float acc = lb[lane];
    #pragma unroll
    for (int dy=0; dy<5; dy++){
      int yy = y+dy-2; if ((unsigned)yy >= (unsigned)HPIX) continue;
      #pragma unroll
      for (int dx=0; dx<5; dx++){
        int x2c = xx+dx-2; if ((unsigned)x2c >= (unsigned)WPIX) continue;
        int pp = (yy>>3)*16 + (x2c>>3), rr = ((yy&7)<<3) + (x2c&7);
        acc += lw[lane*25 + dy*5 + dx] * qkv[(pp*HWIN + rr)*192 + 128 + lane];
      }
    }
    tT[lane*LNS + pl] = attnout[pix*CCH + lane] + acc;
  }
  __syncthreads();

  // Phase B: wo (thread = 2 pix x 2 cols) + x1 residual -> x2T
  {
    int p0 = (tid & 15) * 2;
    int j0 = (tid >> 4) * 2;
    float a00=wb[j0], a01=wb[j0+1], a10=wb[j0], a11=wb[j0+1];
    for (int k0=0; k0<64; k0+=2){
      float2 a0 = *(const float2*)&tT[k0*LNS + p0];
      float2 a1 = *(const float2*)&tT[(k0+1)*LNS + p0];
      float2 u0 = *(const float2*)(ww + k0*64 + j0);
      float2 u1 = *(const float2*)(ww + (k0+1)*64 + j0);
      a00+=a0.x*u0.x; a01+=a0.x*u0.y; a10+=a0.y*u0.x; a11+=a0.y*u0.y;
      a00+=a1.x*u1.x; a01+=a1.x*u1.y; a10+=a1.y*u1.x; a11+=a1.y*u1.y;
    }
    float2 r0 = *(const float2*)(x1 + (pix0+p0)*CCH + j0);
    float2 r1 = *(const float2*)(x1 + (pix0+p0+1)*CCH + j0);
    x2T[j0*LNS + p0]       = r0.x + a00;
    x2T[(j0+1)*LNS + p0]   = r0.y + a01;
    x2T[j0*LNS + p0+1]     = r1.x + a10;
    x2T[(j0+1)*LNS + p0+1] = r1.y + a11;
  }
  __syncthreads();

  // Phase C: LN (wave w -> pixels w*4..w*4+3)
  #pragma unroll
  for (int i=0; i<4; i++){
    int pl = w*4 + i;
    float v = x2T[lane*LNS + pl];
    float mean = waveReduceSum(v) * (1.f/64.f);
    float d = v - mean;
    float var = waveReduceSum(d*d) * (1.f/64.f);
    lnT[lane*LNS + pl] = d * rsqrtf(var + 1e-6f) * g[lane] + bb[lane];
  }
  __syncthreads();

  // Phase D: fc1 + gelu (thread = 4 pix x 4 cols, chunk-2)
  {
    int p0 = (tid & 7) * 4;
    int j0 = (tid >> 3) * 4;
    float acc[4][4];
    #pragma unroll
    for (int i=0;i<4;i++)
      #pragma unroll
      for (int j=0;j<4;j++) acc[i][j] = b1[j0+j];
    for (int k0=0; k0<64; k0+=2){
      float4 a0 = *(const float4*)&lnT[k0*LNS + p0];
      float4 a1 = *(const float4*)&lnT[(k0+1)*LNS + p0];
      float4 u0 = *(const float4*)(w1 + k0*256 + j0);
      float4 u1 = *(const float4*)(w1 + (k0+1)*256 + j0);
      float a0v[4] = {a0.x,a0.y,a0.z,a0.w};
      float a1v[4] = {a1.x,a1.y,a1.z,a1.w};
      #pragma unroll
      for (int i=0;i<4;i++){
        acc[i][0]+=a0v[i]*u0.x; acc[i][1]+=a0v[i]*u0.y;
        acc[i][2]+=a0v[i]*u0.z; acc[i][3]+=a0v[i]*u0.w;
      }
      #pragma unroll
      for (int i=0;i<4;i++){
        acc[i][0]+=a1v[i]*u1.x; acc[i][1]+=a1v[i]*u1.y;
        acc[i][2]+=a1v[i]*u1.z; acc[i][3]+=a1v[i]*u1.w;
      }
    }
    #pragma unroll
    for (int j=0;j<4;j++){
      float4 hv;
      hv.x = gelu_exact(acc[0][j]);
      hv.y = gelu_exact(acc[1][j]);
      hv.z = gelu_exact(acc[2][j]);
      hv.w = gelu_exact(acc[3][j]);
      *(float4*)&hidT[(j0+j)*LNS + p0] = hv;
    }
  }
  __syncthreads();

  // Phase E: fc2. wave: kq = w&3 (64-k quarter), chh = w>>2 (32-col half).
  // lane tile: 4 pix x 4 cols.
  float acc2[4][4];
  {
    int p0 = (lane & 7) * 4;
    int c0 = (w >> 2) * 32 + (lane >> 3) * 4;
    #pragma unroll
    for (int i=0;i<4;i++)
      #pragma unroll
      for (int j=0;j<4;j++) acc2[i][j] = 0.f;
    int kbase = (w & 3) * 64;
    for (int k0=0; k0<64; k0+=2){
      int k = kbase + k0;
      float4 a0 = *(const float4*)&hidT[k*LNS + p0];
      float4 a1 = *(const float4*)&hidT[(k+1)*LNS + p0];
      float4 u0 = *(const float4*)(w2 + k*64 + c0);
      float4 u1 = *(const float4*)(w2 + (k+1)*64 + c0);
      float a0v[4] = {a0.x,a0.y,a0.z,a0.w};
      float a1v[4] = {a1.x,a1.y,a1.z,a1.w};
      #pragma unroll
      for (int i=0;i<4;i++){
        acc2[i][0]+=a0v[i]*u0.x; acc2[i][1]+=a0v[i]*u0.y;
        acc2[i][2]+=a0v[i]*u0.z; acc2[i][3]+=a0v[i]*u0.w;
      }
      #pragma unroll
      for (int i=0;i<4;i++){
        acc2[i][0]+=a1v[i]*u1.x; acc2[i][1]+=a1v[i]*u1.y;
        acc2[i][2]+=a1v[i]*u1.z; acc2[i][3]+=a1v[i]*u1.w;
      }
    }
  }
  __syncthreads();   // hidT dead; overlay red[512][18]
  #pragma unroll
  for (int t=0; t<8; t++){
    int s = 2*t, i = s >> 2, j = s & 3;
    *(float2*)&red[tid*18 + s] = make_float2(acc2[i][j], acc2[i][j+1]);
  }
  __syncthreads();

  // Phase F: reduce 4 K-partials + bias + residual + NCHW store.
  // thread = (pix = tid&31, cq = tid>>5 -> 4 cols)
  {
    int pix_l = tid & 31, cq = tid >> 5;
    int c0 = cq * 4, chh = cq >> 3, cg = cq & 7;
    int pg = pix_l >> 2, ip = pix_l & 3;
    int lane_e = pg | (cg << 3);
    float o[4];
    #pragma unroll
    for (int j=0;j<4;j++) o[j] = b2[c0+j];
    #pragma unroll
    for (int kq=0; kq<4; kq++){
      int we = kq | (chh << 2);
      const float* rp = &red[(we*64 + lane_e)*18 + ip*4];
      float2 pr0 = *(const float2*)(rp);
      float2 pr1 = *(const float2*)(rp + 2);
      o[0] += pr0.x; o[1] += pr0.y; o[2] += pr1.x; o[3] += pr1.y;
    }
    #pragma unroll
    for (int j=0;j<4;j++)
      o[j] += x2T[(c0+j)*LNS + pix_l];
    #pragma unroll
    for (int j=0;j<4;j++)
      out[(c0+j)*NPIX + pix0 + pix_l] = o[j];
  }
}

extern "C" void kernel_launch(void* const* d_in, const int* in_sizes, int n_in,
                              void* d_out, int out_size, void* d_ws, size_t ws_size,
                              hipStream_t stream) {
  (void)in_sizes; (void)n_in; (void)out_size; (void)ws_size;
  const float* x      = (const float*)d_in[0];
  const float* pos_w  = (const float*)d_in[1];
  const float* pos_b  = (const float*)d_in[2];
  const float* norm_g = (const float*)d_in[3];
  const float* norm_b = (const float*)d_in[4];
  const float* qkv_w  = (const float*)d_in[5];
  const float* qkv_b  = (const float*)d_in[6];
  const float* wo_w   = (const float*)d_in[7];
  const float* wo_b   = (const float*)d_in[8];
  const float* lepe_w = (const float*)d_in[9];
  const float* lepe_b = (const float*)d_in[10];
  const float* mlp_w1 = (const float*)d_in[11];
  const float* mlp_b1 = (const float*)d_in[12];
  const float* mlp_w2 = (const float*)d_in[13];
  const float* mlp_b2 = (const float*)d_in[14];
  float* out = (float*)d_out;

  char* ws = (char*)d_ws;
  float* x1      = (float*)(ws);                          // 4 MB
  float* qkv     = (float*)(ws + (4u<<20));               // 12 MB [p][r][192]
  float* qwin    = (float*)(ws + (16u<<20));              // 64 KB
  float* kwinT   = (float*)(ws + (16u<<20) + (64u<<10));  // 64 KB  [c][p]
  int*   idx     = (int*)  (ws + (16u<<20) + (128u<<10)); // 4 KB
  float* attnout = (float*)(ws + (17u<<20));              // 4 MB (NHWC)

  hipLaunchKernelGGL(k1_posconv,      dim3(4096), dim3(256), 0, stream, x, pos_w, pos_b, x1);
  hipLaunchKernelGGL(k2_ln_qkv,       dim3(512),  dim3(256), 0, stream, x1, norm_g, norm_b, qkv_w, qkv_b, qkv);
  hipLaunchKernelGGL(k3_winmean,      dim3(256),  dim3(256), 0, stream, qkv, qwin, kwinT);
  hipLaunchKernelGGL(k4_topk,         dim3(256),  dim3(256), 0, stream, qwin, kwinT, idx);
  hipLaunchKernelGGL(k5_attn,         dim3(2048), dim3(256), 0, stream, qkv, idx, attnout);
  hipLaunchKernelGGL(k67_lepe_wo_mlp, dim3(512),  dim3(512), 0, stream, attnout, qkv,
                     lepe_w, lepe_b, wo_w, wo_b, x1, norm_g, norm_b,
                     mlp_w1, mlp_b1, mlp_w2, mlp_b2, out);
}

// Round 12
// 195.714 us; speedup vs baseline: 1.0447x; 1.0447x over previous
//
#include <hip/hip_runtime.h>
#include <hip/hip_bf16.h>
#include <math.h>

#define HPIX 128
#define WPIX 128
#define NPIX (HPIX*WPIX)   // 16384
#define CCH 64
#define P2 256             // number of windows (16x16)
#define HWIN 64            // pixels per window (8x8)
#define LNS 36             // LDS row stride (floats), 144B, 16B-aligned

__device__ __forceinline__ float waveReduceSum(float v){
  #pragma unroll
  for (int m = 32; m >= 1; m >>= 1) v += __shfl_xor(v, m);
  return v;
}

__device__ __forceinline__ float gelu_exact(float h){
  return 0.5f*h*(1.f + erff(h*0.70710678118654752f));
}

// K1: x1(NHWC,f32) = x + dwconv3x3(x,pos_w,pos_b). LDS-staged rows. (round-9)
__global__ void k1_posconv(const float* __restrict__ x, const float* __restrict__ pw,
                           const float* __restrict__ pb, float* __restrict__ x1){
  __shared__ float tile[4][3][72];
  __shared__ float lds[4][64];
  int tid = threadIdx.x;
  int pl = tid & 63, cl = tid >> 6;
  int pix0 = (blockIdx.x & 255) * 64;
  int cg   = (blockIdx.x >> 8);
  int c = cg*4 + cl;
  int y  = pix0 >> 7;
  int xb = pix0 & 127;
  const float* xc = x + c*NPIX;
  for (int t = pl; t < 3*66; t += 64){
    int r = t / 66, ccol = t - r*66;
    int yy = y - 1 + r, xxr = xb - 1 + ccol;
    float v = 0.f;
    if ((unsigned)yy < (unsigned)HPIX && (unsigned)xxr < (unsigned)WPIX)
      v = xc[yy*WPIX + xxr];
    tile[cl][r][ccol] = v;
  }
  float wreg[9];
  #pragma unroll
  for (int t=0;t<9;t++) wreg[t] = pw[c*9+t];
  float bias = pb[c];
  __syncthreads();
  float acc = bias;
  #pragma unroll
  for (int dy=0;dy<3;dy++)
    #pragma unroll
    for (int dx=0;dx<3;dx++)
      acc += wreg[dy*3+dx] * tile[cl][dy][pl+dx];
  lds[cl][pl] = tile[cl][1][pl+1] + acc;
  __syncthreads();
  int pp = tid >> 2, cc = tid & 3;
  x1[(pix0+pp)*CCH + cg*4 + cc] = lds[cc][pp];
}

// K2: LN + qkv. 32 px/block, 256 thr, grid 512. (round-10 proven)
__global__ void k2_ln_qkv(const float* __restrict__ x1,
                          const float* __restrict__ g, const float* __restrict__ bb,
                          const float* __restrict__ qw, const float* __restrict__ qb,
                          float* __restrict__ qkv){
  __shared__ __align__(16) float lnT[64][LNS];
  int tid = threadIdx.x, w = tid >> 6, lane = tid & 63;
  int pix0 = blockIdx.x * 32;
  #pragma unroll
  for (int i=0; i<8; i++){
    int pl = w*8 + i, pix = pix0 + pl;
    float v = x1[pix*CCH + lane];
    float mean = waveReduceSum(v) * (1.f/64.f);
    float d = v - mean;
    float var = waveReduceSum(d*d) * (1.f/64.f);
    lnT[lane][pl] = d * rsqrtf(var + 1e-6f) * g[lane] + bb[lane];
  }
  __syncthreads();
  int p0 = (tid & 7) * 4;
  int cg = tid >> 3;
  int j0 = cg * 6;
  float acc[4][6];
  #pragma unroll
  for (int i=0;i<4;i++)
    #pragma unroll
    for (int j=0;j<6;j++) acc[i][j] = qb[j0+j];
  for (int k0=0; k0<64; k0+=2){
    float4 a0 = *(const float4*)&lnT[k0][p0];
    float4 a1 = *(const float4*)&lnT[k0+1][p0];
    const float* wr0 = qw + k0*192 + j0;
    const float* wr1 = wr0 + 192;
    float2 u00 = *(const float2*)(wr0);
    float2 u01 = *(const float2*)(wr0+2);
    float2 u02 = *(const float2*)(wr0+4);
    float2 u10 = *(const float2*)(wr1);
    float2 u11 = *(const float2*)(wr1+2);
    float2 u12 = *(const float2*)(wr1+4);
    float a0v[4] = {a0.x,a0.y,a0.z,a0.w};
    float a1v[4] = {a1.x,a1.y,a1.z,a1.w};
    #pragma unroll
    for (int i=0;i<4;i++){
      acc[i][0]+=a0v[i]*u00.x; acc[i][1]+=a0v[i]*u00.y;
      acc[i][2]+=a0v[i]*u01.x; acc[i][3]+=a0v[i]*u01.y;
      acc[i][4]+=a0v[i]*u02.x; acc[i][5]+=a0v[i]*u02.y;
    }
    #pragma unroll
    for (int i=0;i<4;i++){
      acc[i][0]+=a1v[i]*u10.x; acc[i][1]+=a1v[i]*u10.y;
      acc[i][2]+=a1v[i]*u11.x; acc[i][3]+=a1v[i]*u11.y;
      acc[i][4]+=a1v[i]*u12.x; acc[i][5]+=a1v[i]*u12.y;
    }
  }
  int y = pix0 >> 7;
  int pb_row = (y>>3)*16, rrow = (y&7)<<3, xbase = pix0 & 127;
  #pragma unroll
  for (int i=0;i<4;i++){
    int xx = xbase + p0 + i;
    int p = pb_row + (xx>>3);
    int r = rrow + (xx&7);
    float* o = qkv + (p*HWIN + r)*192 + j0;
    *(float2*)(o)     = make_float2(acc[i][0], acc[i][1]);
    *(float2*)(o + 2) = make_float2(acc[i][2], acc[i][3]);
    *(float2*)(o + 4) = make_float2(acc[i][4], acc[i][5]);
  }
}

// K3: per-window means; kwin stored TRANSPOSED [c][p].
__global__ void k3_winmean(const float* __restrict__ qkv,
                           float* __restrict__ qwin, float* __restrict__ kwinT){
  int p = blockIdx.x;
  int tid = threadIdx.x, rq = tid >> 6, c = tid & 63;
  float sq = 0.f, sk = 0.f;
  for (int r = rq*16; r < rq*16+16; r++){
    const float* row = qkv + (p*HWIN + r)*192;
    sq += row[c];
    sk += row[64 + c];
  }
  __shared__ float s1[4][64], s2[4][64];
  s1[rq][c] = sq; s2[rq][c] = sk;
  __syncthreads();
  if (tid < 64){
    qwin[p*64 + c]   = (s1[0][c]+s1[1][c]+s1[2][c]+s1[3][c])*(1.f/64.f);
    kwinT[c*P2 + p]  = (s2[0][c]+s2[1][c]+s2[2][c]+s2[3][c])*(1.f/64.f);
  }
}

// K4: logits + top-4 (desc, ties -> lowest index).
__global__ void k4_topk(const float* __restrict__ qwin, const float* __restrict__ kwinT,
                        int* __restrict__ idx){
  int p = blockIdx.x, t = threadIdx.x;
  int w = t >> 6, lane = t & 63;
  __shared__ float qs[64];
  __shared__ float lg[P2];
  __shared__ float wv[4]; __shared__ int wi[4];
  if (t < 64) qs[t] = qwin[p*64 + t];
  __syncthreads();
  float acc = 0.f;
  #pragma unroll 8
  for (int c=0; c<64; c++) acc += qs[c] * kwinT[c*P2 + t];
  lg[t] = acc;
  __syncthreads();
  for (int j=0; j<4; j++){
    float v = lg[t]; int i = t;
    #pragma unroll
    for (int m=32; m>=1; m>>=1){
      float ov = __shfl_xor(v, m); int oi = __shfl_xor(i, m);
      if (ov > v || (ov == v && oi < i)){ v = ov; i = oi; }
    }
    if (lane == 0){ wv[w] = v; wi[w] = i; }
    __syncthreads();
    if (t == 0){
      float bv = wv[0]; int bi = wi[0];
      #pragma unroll
      for (int u=1; u<4; u++)
        if (wv[u] > bv || (wv[u] == bv && wi[u] < bi)){ bv = wv[u]; bi = wi[u]; }
      idx[p*4 + j] = bi;
      lg[bi] = -1e30f;
    }
    __syncthreads();
  }
}

// K5: attention (window p, head n). 4 waves split 256 keys; distributed merge
// with COALESCED writes (4-lane d-groups per pixel -> 32B contiguous stores).
__global__ void k5_attn(const float* __restrict__ qkv, const int* __restrict__ idx,
                        float* __restrict__ attnout){
  int p = blockIdx.x >> 3, n = blockIdx.x & 7;
  int tid = threadIdx.x, w = tid >> 6, lane = tid & 63;
  __shared__ float Ks[256][8];
  __shared__ float Vs[256][8];
  __shared__ int wsel[4];
  __shared__ float ps_tail[256];
  (void)ps_tail;
  float* psbuf = &Ks[0][0];
  if (tid < 4) wsel[tid] = idx[p*4 + tid];
  __syncthreads();
  int cb = n*8;
  for (int u = tid; u < 512; u += 256){
    int k = u >> 1, h = u & 1;
    const float* row = qkv + (wsel[k>>6]*HWIN + (k&63))*192;
    *(float4*)&Ks[k][h*4] = *(const float4*)(row + 64  + cb + h*4);
    *(float4*)&Vs[k][h*4] = *(const float4*)(row + 128 + cb + h*4);
  }
  __syncthreads();
  const float* qrow = qkv + (p*HWIN + lane)*192 + cb;
  float4 q0 = *(const float4*)(qrow);
  float4 q1 = *(const float4*)(qrow + 4);
  float q[8] = {q0.x*0.125f, q0.y*0.125f, q0.z*0.125f, q0.w*0.125f,
                q1.x*0.125f, q1.y*0.125f, q1.z*0.125f, q1.w*0.125f};
  float l = 0.f, acc[8];
  #pragma unroll
  for (int d=0; d<8; d++) acc[d] = 0.f;
  #pragma unroll 4
  for (int k = w*64; k < w*64+64; k++){
    float4 ka = *(float4*)&Ks[k][0];
    float4 kb = *(float4*)&Ks[k][4];
    float s = q[0]*ka.x + q[1]*ka.y + q[2]*ka.z + q[3]*ka.w
            + q[4]*kb.x + q[5]*kb.y + q[6]*kb.z + q[7]*kb.w;
    float e = __expf(s);
    l += e;
    float4 va = *(float4*)&Vs[k][0];
    float4 vb = *(float4*)&Vs[k][4];
    acc[0]+=e*va.x; acc[1]+=e*va.y; acc[2]+=e*va.z; acc[3]+=e*va.w;
    acc[4]+=e*vb.x; acc[5]+=e*vb.y; acc[6]+=e*vb.z; acc[7]+=e*vb.w;
  }
  __syncthreads();
  float* myp = psbuf + (w*64 + lane)*9;
  #pragma unroll
  for (int d=0; d<8; d++) myp[d] = acc[d];
  myp[8] = l;
  __syncthreads();
  {
    // thread = (pixel qi, d-pair): lanes 0-3 cover d0=0,2,4,6 of one pixel
    int qi = (w << 4) + (lane >> 2);
    int d0 = (lane & 3) * 2;
    float L = 0.f, o0 = 0.f, o1 = 0.f;
    #pragma unroll
    for (int u=0; u<4; u++){
      const float* pp2 = psbuf + (u*64 + qi)*9;
      L  += pp2[8];
      o0 += pp2[d0];
      o1 += pp2[d0+1];
    }
    float inv = 1.f / L;
    int yy = (p>>4)*8 + (qi>>3), xx = (p&15)*8 + (qi&7);
    float* orow = attnout + (yy*WPIX + xx)*CCH + cb + d0;
    *(float2*)orow = make_float2(o0*inv, o1*inv);
  }
}

// K67: fused lepe+wo+LN+MLP. 32 px/block, grid 512, block 256. (round-10 proven)
__global__ void k67_lepe_wo_mlp(const float* __restrict__ attnout,
                                const float* __restrict__ qkv,
                                const float* __restrict__ lw, const float* __restrict__ lb,
                                const float* __restrict__ ww, const float* __restrict__ wb,
                                const float* __restrict__ x1,
                                const float* __restrict__ g, const float* __restrict__ bb,
                                const float* __restrict__ w1, const float* __restrict__ b1,
                                const float* __restrict__ w2, const float* __restrict__ b2,
                                float* __restrict__ out){
  __shared__ __align__(16) float smem[13824];            // 55.3 KB
  float* x2T  = smem;                                    // [64][36]
  float* lnT  = smem + 2304;                             // [64][36]
  float* hidT = smem + 4608;                             // [256][36]
  float* tT   = hidT;                                    // alias (dead before D)
  float* red  = hidT;                                    // alias (after E)
  int tid = threadIdx.x, w = tid >> 6, lane = tid & 63;
  int pix0 = blockIdx.x * 32;

  // Phase A: lepe (lane = channel, 8 pixels per wave)
  for (int i=0; i<8; i++){
    int pl = w*8 + i, pix = pix0 + pl;
    int y = pix >> 7, xx = pix & 127;
    float acc = lb[lane];
    #pragma unroll
    for (int dy=0; dy<5; dy++){
      int yy = y+dy-2; if ((unsigned)yy >= (unsigned)HPIX) continue;
      #pragma unroll
      for (int dx=0; dx<5; dx++){
        int x2c = xx+dx-2; if ((unsigned)x2c >= (unsigned)WPIX) continue;
        int pp = (yy>>3)*16 + (x2c>>3), rr = ((yy&7)<<3) + (x2c&7);
        acc += lw[lane*25 + dy*5 + dx] * qkv[(pp*HWIN + rr)*192 + 128 + lane];
      }
    }
    tT[lane*LNS + pl] = attnout[pix*CCH + lane] + acc;
  }
  __syncthreads();

  // Phase B: wo matmul (4 pix x 2 cols) + x1 residual -> x2T (LDS only)
  {
    int p0 = (tid & 7) * 4;
    int cg = tid >> 3;
    int j0 = cg * 2;
    float a0[4], a1[4];
    #pragma unroll
    for (int i=0;i<4;i++){ a0[i] = wb[j0]; a1[i] = wb[j0+1]; }
    #pragma unroll 4
    for (int k=0; k<64; k++){
      float4 a = *(const float4*)&tT[k*LNS + p0];
      float2 u = *(const float2*)(ww + k*64 + j0);
      a0[0]+=a.x*u.x; a1[0]+=a.x*u.y;
      a0[1]+=a.y*u.x; a1[1]+=a.y*u.y;
      a0[2]+=a.z*u.x; a1[2]+=a.z*u.y;
      a0[3]+=a.w*u.x; a1[3]+=a.w*u.y;
    }
    #pragma unroll
    for (int i=0;i<4;i++){
      int pix = pix0 + p0 + i;
      float2 r = *(const float2*)(x1 + pix*CCH + j0);
      x2T[j0*LNS + p0 + i]     = r.x + a0[i];
      x2T[(j0+1)*LNS + p0 + i] = r.y + a1[i];
    }
  }
  __syncthreads();

  // Phase C: LN from x2T
  #pragma unroll
  for (int i=0; i<8; i++){
    int pl = w*8 + i;
    float v = x2T[lane*LNS + pl];
    float mean = waveReduceSum(v) * (1.f/64.f);
    float d = v - mean;
    float var = waveReduceSum(d*d) * (1.f/64.f);
    lnT[lane*LNS + pl] = d * rsqrtf(var + 1e-6f) * g[lane] + bb[lane];
  }
  __syncthreads();

  // Phase D: fc1 + gelu (4 pix x 8 cols, chunk-2)
  {
    int p0 = (tid & 7) * 4;
    int j0 = (tid >> 3) * 8;
    float acc[4][8];
    #pragma unroll
    for (int i=0;i<4;i++)
      #pragma unroll
      for (int j=0;j<8;j++) acc[i][j] = b1[j0+j];
    for (int k0=0; k0<64; k0+=2){
      float4 a0 = *(const float4*)&lnT[k0*LNS + p0];
      float4 a1 = *(const float4*)&lnT[(k0+1)*LNS + p0];
      const float* wr0 = w1 + k0*256 + j0;
      const float* wr1 = wr0 + 256;
      float4 u00 = *(const float4*)(wr0);
      float4 u01 = *(const float4*)(wr0+4);
      float4 u10 = *(const float4*)(wr1);
      float4 u11 = *(const float4*)(wr1+4);
      float a0v[4] = {a0.x,a0.y,a0.z,a0.w};
      float a1v[4] = {a1.x,a1.y,a1.z,a1.w};
      #pragma unroll
      for (int i=0;i<4;i++){
        acc[i][0]+=a0v[i]*u00.x; acc[i][1]+=a0v[i]*u00.y;
        acc[i][2]+=a0v[i]*u00.z; acc[i][3]+=a0v[i]*u00.w;
        acc[i][4]+=a0v[i]*u01.x; acc[i][5]+=a0v[i]*u01.y;
        acc[i][6]+=a0v[i]*u01.z; acc[i][7]+=a0v[i]*u01.w;
      }
      #pragma unroll
      for (int i=0;i<4;i++){
        acc[i][0]+=a1v[i]*u10.x; acc[i][1]+=a1v[i]*u10.y;
        acc[i][2]+=a1v[i]*u10.z; acc[i][3]+=a1v[i]*u10.w;
        acc[i][4]+=a1v[i]*u11.x; acc[i][5]+=a1v[i]*u11.y;
        acc[i][6]+=a1v[i]*u11.z; acc[i][7]+=a1v[i]*u11.w;
      }
    }
    #pragma unroll
    for (int j=0;j<8;j++){
      float4 hv;
      hv.x = gelu_exact(acc[0][j]);
      hv.y = gelu_exact(acc[1][j]);
      hv.z = gelu_exact(acc[2][j]);
      hv.w = gelu_exact(acc[3][j]);
      *(float4*)&hidT[(j0+j)*LNS + p0] = hv;
    }
  }
  __syncthreads();

  // Phase E: fc2 K-split across 4 waves (4 pix x 8 cols, chunk-2)
  float acc2[4][8];
  {
    int p0 = (lane & 7) * 4;
    int c0 = (lane >> 3) * 8;
    #pragma unroll
    for (int i=0;i<4;i++)
      #pragma unroll
      for (int j=0;j<8;j++) acc2[i][j] = 0.f;
    int kbase = w*64;
    for (int k0=0; k0<64; k0+=2){
      int k = kbase + k0;
      float4 a0 = *(const float4*)&hidT[k*LNS + p0];
      float4 a1 = *(const float4*)&hidT[(k+1)*LNS + p0];
      const float* wr0 = w2 + k*64 + c0;
      const float* wr1 = wr0 + 64;
      float4 u00 = *(const float4*)(wr0);
      float4 u01 = *(const float4*)(wr0+4);
      float4 u10 = *(const float4*)(wr1);
      float4 u11 = *(const float4*)(wr1+4);
      float a0v[4] = {a0.x,a0.y,a0.z,a0.w};
      float a1v[4] = {a1.x,a1.y,a1.z,a1.w};
      #pragma unroll
      for (int i=0;i<4;i++){
        acc2[i][0]+=a0v[i]*u00.x; acc2[i][1]+=a0v[i]*u00.y;
        acc2[i][2]+=a0v[i]*u00.z; acc2[i][3]+=a0v[i]*u00.w;
        acc2[i][4]+=a0v[i]*u01.x; acc2[i][5]+=a0v[i]*u01.y;
        acc2[i][6]+=a0v[i]*u01.z; acc2[i][7]+=a0v[i]*u01.w;
      }
      #pragma unroll
      for (int i=0;i<4;i++){
        acc2[i][0]+=a1v[i]*u10.x; acc2[i][1]+=a1v[i]*u10.y;
        acc2[i][2]+=a1v[i]*u10.z; acc2[i][3]+=a1v[i]*u10.w;
        acc2[i][4]+=a1v[i]*u11.x; acc2[i][5]+=a1v[i]*u11.y;
        acc2[i][6]+=a1v[i]*u11.z; acc2[i][7]+=a1v[i]*u11.w;
      }
    }
  }
  __syncthreads();   // hidT dead; overlay red
  #pragma unroll
  for (int t=0; t<16; t++){
    int s = 2*t, i = s >> 3, j = s & 7;
    *(float2*)&red[tid*34 + s] = make_float2(acc2[i][j], acc2[i][j+1]);
  }
  __syncthreads();

  // Phase F: reduce partials + bias + residual (from x2T) + NCHW store
  {
    int lane_r = tid & 63, ir = tid >> 6;
    int pg = lane_r & 7, cgf = lane_r >> 3;
    int pix = pix0 + pg*4 + ir;
    int c0 = cgf*8;
    float o[8];
    #pragma unroll
    for (int j=0;j<8;j++) o[j] = b2[c0+j];
    #pragma unroll
    for (int wq=0; wq<4; wq++){
      const float* rp = &red[(wq*64 + lane_r)*34 + ir*8];
      #pragma unroll
      for (int j2=0;j2<4;j2++){
        float2 pr = *(const float2*)(rp + 2*j2);
        o[2*j2]   += pr.x;
        o[2*j2+1] += pr.y;
      }
    }
    int plocal = pg*4 + ir;
    #pragma unroll
    for (int j=0;j<8;j++)
      o[j] += x2T[(c0+j)*LNS + plocal];
    #pragma unroll
    for (int j=0;j<8;j++)
      out[(c0+j)*NPIX + pix] = o[j];
  }
}

extern "C" void kernel_launch(void* const* d_in, const int* in_sizes, int n_in,
                              void* d_out, int out_size, void* d_ws, size_t ws_size,
                              hipStream_t stream) {
  (void)in_sizes; (void)n_in; (void)out_size; (void)ws_size;
  const float* x      = (const float*)d_in[0];
  const float* pos_w  = (const float*)d_in[1];
  const float* pos_b  = (const float*)d_in[2];
  const float* norm_g = (const float*)d_in[3];
  const float* norm_b = (const float*)d_in[4];
  const float* qkv_w  = (const float*)d_in[5];
  const float* qkv_b  = (const float*)d_in[6];
  const float* wo_w   = (const float*)d_in[7];
  const float* wo_b   = (const float*)d_in[8];
  const float* lepe_w = (const float*)d_in[9];
  const float* lepe_b = (const float*)d_in[10];
  const float* mlp_w1 = (const float*)d_in[11];
  const float* mlp_b1 = (const float*)d_in[12];
  const float* mlp_w2 = (const float*)d_in[13];
  const float* mlp_b2 = (const float*)d_in[14];
  float* out = (float*)d_out;

  char* ws = (char*)d_ws;
  float* x1      = (float*)(ws);                          // 4 MB
  float* qkv     = (float*)(ws + (4u<<20));               // 12 MB [p][r][192]
  float* qwin    = (float*)(ws + (16u<<20));              // 64 KB
  float* kwinT   = (float*)(ws + (16u<<20) + (64u<<10));  // 64 KB  [c][p]
  int*   idx     = (int*)  (ws + (16u<<20) + (128u<<10)); // 4 KB
  float* attnout = (float*)(ws + (17u<<20));              // 4 MB (NHWC)

  hipLaunchKernelGGL(k1_posconv,      dim3(4096), dim3(256), 0, stream, x, pos_w, pos_b, x1);
  hipLaunchKernelGGL(k2_ln_qkv,       dim3(512),  dim3(256), 0, stream, x1, norm_g, norm_b, qkv_w, qkv_b, qkv);
  hipLaunchKernelGGL(k3_winmean,      dim3(256),  dim3(256), 0, stream, qkv, qwin, kwinT);
  hipLaunchKernelGGL(k4_topk,         dim3(256),  dim3(256), 0, stream, qwin, kwinT, idx);
  hipLaunchKernelGGL(k5_attn,         dim3(2048), dim3(256), 0, stream, qkv, idx, attnout);
  hipLaunchKernelGGL(k67_lepe_wo_mlp, dim3(512),  dim3(256), 0, stream, attnout, qkv,
                     lepe_w, lepe_b, wo_w, wo_b, x1, norm_g, norm_b,
                     mlp_w1, mlp_b1, mlp_w2, mlp_b2, out);
}

// Round 13
// 192.196 us; speedup vs baseline: 1.0638x; 1.0183x over previous
//
#include <hip/hip_runtime.h>
#include <hip/hip_bf16.h>
#include <math.h>

#define HPIX 128
#define WPIX 128
#define NPIX (HPIX*WPIX)   // 16384
#define CCH 64
#define P2 256             // number of windows (16x16)
#define HWIN 64            // pixels per window (8x8)
#define LNS 36             // LDS row stride (floats), 144B, 16B-aligned

__device__ __forceinline__ float waveReduceSum(float v){
  #pragma unroll
  for (int m = 32; m >= 1; m >>= 1) v += __shfl_xor(v, m);
  return v;
}

__device__ __forceinline__ float gelu_exact(float h){
  return 0.5f*h*(1.f + erff(h*0.70710678118654752f));
}

// K1: x1(NHWC,f32) = x + dwconv3x3(x,pos_w,pos_b). LDS-staged rows. (round-9)
__global__ void k1_posconv(const float* __restrict__ x, const float* __restrict__ pw,
                           const float* __restrict__ pb, float* __restrict__ x1){
  __shared__ float tile[4][3][72];
  __shared__ float lds[4][64];
  int tid = threadIdx.x;
  int pl = tid & 63, cl = tid >> 6;
  int pix0 = (blockIdx.x & 255) * 64;
  int cg   = (blockIdx.x >> 8);
  int c = cg*4 + cl;
  int y  = pix0 >> 7;
  int xb = pix0 & 127;
  const float* xc = x + c*NPIX;
  for (int t = pl; t < 3*66; t += 64){
    int r = t / 66, ccol = t - r*66;
    int yy = y - 1 + r, xxr = xb - 1 + ccol;
    float v = 0.f;
    if ((unsigned)yy < (unsigned)HPIX && (unsigned)xxr < (unsigned)WPIX)
      v = xc[yy*WPIX + xxr];
    tile[cl][r][ccol] = v;
  }
  float wreg[9];
  #pragma unroll
  for (int t=0;t<9;t++) wreg[t] = pw[c*9+t];
  float bias = pb[c];
  __syncthreads();
  float acc = bias;
  #pragma unroll
  for (int dy=0;dy<3;dy++)
    #pragma unroll
    for (int dx=0;dx<3;dx++)
      acc += wreg[dy*3+dx] * tile[cl][dy][pl+dx];
  lds[cl][pl] = tile[cl][1][pl+1] + acc;
  __syncthreads();
  int pp = tid >> 2, cc = tid & 3;
  x1[(pix0+pp)*CCH + cg*4 + cc] = lds[cc][pp];
}

// K2: LN + qkv. 32 px/block, 256 thr, grid 512. chunk-4 + launch_bounds.
__global__ void __launch_bounds__(256, 2)
k2_ln_qkv(const float* __restrict__ x1,
          const float* __restrict__ g, const float* __restrict__ bb,
          const float* __restrict__ qw, const float* __restrict__ qb,
          float* __restrict__ qkv){
  __shared__ __align__(16) float lnT[64][LNS];
  int tid = threadIdx.x, w = tid >> 6, lane = tid & 63;
  int pix0 = blockIdx.x * 32;
  #pragma unroll
  for (int i=0; i<8; i++){
    int pl = w*8 + i, pix = pix0 + pl;
    float v = x1[pix*CCH + lane];
    float mean = waveReduceSum(v) * (1.f/64.f);
    float d = v - mean;
    float var = waveReduceSum(d*d) * (1.f/64.f);
    lnT[lane][pl] = d * rsqrtf(var + 1e-6f) * g[lane] + bb[lane];
  }
  __syncthreads();
  int p0 = (tid & 7) * 4;
  int cg = tid >> 3;
  int j0 = cg * 6;
  float acc[4][6];
  #pragma unroll
  for (int i=0;i<4;i++)
    #pragma unroll
    for (int j=0;j<6;j++) acc[i][j] = qb[j0+j];
  for (int k0=0; k0<64; k0+=4){
    float4 a[4]; float2 u[4][3];
    #pragma unroll
    for (int t=0;t<4;t++){
      a[t] = *(const float4*)&lnT[k0+t][p0];
      const float* wr = qw + (k0+t)*192 + j0;
      u[t][0] = *(const float2*)(wr);
      u[t][1] = *(const float2*)(wr+2);
      u[t][2] = *(const float2*)(wr+4);
    }
    #pragma unroll
    for (int t=0;t<4;t++){
      float av[4] = {a[t].x, a[t].y, a[t].z, a[t].w};
      #pragma unroll
      for (int i=0;i<4;i++){
        acc[i][0]+=av[i]*u[t][0].x; acc[i][1]+=av[i]*u[t][0].y;
        acc[i][2]+=av[i]*u[t][1].x; acc[i][3]+=av[i]*u[t][1].y;
        acc[i][4]+=av[i]*u[t][2].x; acc[i][5]+=av[i]*u[t][2].y;
      }
    }
  }
  int y = pix0 >> 7;
  int pb_row = (y>>3)*16, rrow = (y&7)<<3, xbase = pix0 & 127;
  #pragma unroll
  for (int i=0;i<4;i++){
    int xx = xbase + p0 + i;
    int p = pb_row + (xx>>3);
    int r = rrow + (xx&7);
    float* o = qkv + (p*HWIN + r)*192 + j0;
    *(float2*)(o)     = make_float2(acc[i][0], acc[i][1]);
    *(float2*)(o + 2) = make_float2(acc[i][2], acc[i][3]);
    *(float2*)(o + 4) = make_float2(acc[i][4], acc[i][5]);
  }
}

// K3: per-window means; kwin stored TRANSPOSED [c][p].
__global__ void k3_winmean(const float* __restrict__ qkv,
                           float* __restrict__ qwin, float* __restrict__ kwinT){
  int p = blockIdx.x;
  int tid = threadIdx.x, rq = tid >> 6, c = tid & 63;
  float sq = 0.f, sk = 0.f;
  for (int r = rq*16; r < rq*16+16; r++){
    const float* row = qkv + (p*HWIN + r)*192;
    sq += row[c];
    sk += row[64 + c];
  }
  __shared__ float s1[4][64], s2[4][64];
  s1[rq][c] = sq; s2[rq][c] = sk;
  __syncthreads();
  if (tid < 64){
    qwin[p*64 + c]   = (s1[0][c]+s1[1][c]+s1[2][c]+s1[3][c])*(1.f/64.f);
    kwinT[c*P2 + p]  = (s2[0][c]+s2[1][c]+s2[2][c]+s2[3][c])*(1.f/64.f);
  }
}

// K4: logits + top-4 (desc, ties -> lowest index).
__global__ void k4_topk(const float* __restrict__ qwin, const float* __restrict__ kwinT,
                        int* __restrict__ idx){
  int p = blockIdx.x, t = threadIdx.x;
  int w = t >> 6, lane = t & 63;
  __shared__ float qs[64];
  __shared__ float lg[P2];
  __shared__ float wv[4]; __shared__ int wi[4];
  if (t < 64) qs[t] = qwin[p*64 + t];
  __syncthreads();
  float acc = 0.f;
  #pragma unroll 8
  for (int c=0; c<64; c++) acc += qs[c] * kwinT[c*P2 + t];
  lg[t] = acc;
  __syncthreads();
  for (int j=0; j<4; j++){
    float v = lg[t]; int i = t;
    #pragma unroll
    for (int m=32; m>=1; m>>=1){
      float ov = __shfl_xor(v, m); int oi = __shfl_xor(i, m);
      if (ov > v || (ov == v && oi < i)){ v = ov; i = oi; }
    }
    if (lane == 0){ wv[w] = v; wi[w] = i; }
    __syncthreads();
    if (t == 0){
      float bv = wv[0]; int bi = wi[0];
      #pragma unroll
      for (int u=1; u<4; u++)
        if (wv[u] > bv || (wv[u] == bv && wi[u] < bi)){ bv = wv[u]; bi = wi[u]; }
      idx[p*4 + j] = bi;
      lg[bi] = -1e30f;
    }
    __syncthreads();
  }
}

// K5: attention (window p, head n). 4 waves split 256 keys; distributed merge
// with coalesced writes. grid 2048, block 256. (round-12 proven)
__global__ void k5_attn(const float* __restrict__ qkv, const int* __restrict__ idx,
                        float* __restrict__ attnout){
  int p = blockIdx.x >> 3, n = blockIdx.x & 7;
  int tid = threadIdx.x, w = tid >> 6, lane = tid & 63;
  __shared__ float Ks[256][8];
  __shared__ float Vs[256][8];
  __shared__ int wsel[4];
  __shared__ float ps_tail[256];
  (void)ps_tail;
  float* psbuf = &Ks[0][0];
  if (tid < 4) wsel[tid] = idx[p*4 + tid];
  __syncthreads();
  int cb = n*8;
  for (int u = tid; u < 512; u += 256){
    int k = u >> 1, h = u & 1;
    const float* row = qkv + (wsel[k>>6]*HWIN + (k&63))*192;
    *(float4*)&Ks[k][h*4] = *(const float4*)(row + 64  + cb + h*4);
    *(float4*)&Vs[k][h*4] = *(const float4*)(row + 128 + cb + h*4);
  }
  __syncthreads();
  const float* qrow = qkv + (p*HWIN + lane)*192 + cb;
  float4 q0 = *(const float4*)(qrow);
  float4 q1 = *(const float4*)(qrow + 4);
  float q[8] = {q0.x*0.125f, q0.y*0.125f, q0.z*0.125f, q0.w*0.125f,
                q1.x*0.125f, q1.y*0.125f, q1.z*0.125f, q1.w*0.125f};
  float l = 0.f, acc[8];
  #pragma unroll
  for (int d=0; d<8; d++) acc[d] = 0.f;
  #pragma unroll 4
  for (int k = w*64; k < w*64+64; k++){
    float4 ka = *(float4*)&Ks[k][0];
    float4 kb = *(float4*)&Ks[k][4];
    float s = q[0]*ka.x + q[1]*ka.y + q[2]*ka.z + q[3]*ka.w
            + q[4]*kb.x + q[5]*kb.y + q[6]*kb.z + q[7]*kb.w;
    float e = __expf(s);
    l += e;
    float4 va = *(float4*)&Vs[k][0];
    float4 vb = *(float4*)&Vs[k][4];
    acc[0]+=e*va.x; acc[1]+=e*va.y; acc[2]+=e*va.z; acc[3]+=e*va.w;
    acc[4]+=e*vb.x; acc[5]+=e*vb.y; acc[6]+=e*vb.z; acc[7]+=e*vb.w;
  }
  __syncthreads();
  float* myp = psbuf + (w*64 + lane)*9;
  #pragma unroll
  for (int d=0; d<8; d++) myp[d] = acc[d];
  myp[8] = l;
  __syncthreads();
  {
    int qi = (w << 4) + (lane >> 2);
    int d0 = (lane & 3) * 2;
    float L = 0.f, o0 = 0.f, o1 = 0.f;
    #pragma unroll
    for (int u=0; u<4; u++){
      const float* pp2 = psbuf + (u*64 + qi)*9;
      L  += pp2[8];
      o0 += pp2[d0];
      o1 += pp2[d0+1];
    }
    float inv = 1.f / L;
    int yy = (p>>4)*8 + (qi>>3), xx = (p&15)*8 + (qi&7);
    float* orow = attnout + (yy*WPIX + xx)*CCH + cb + d0;
    *(float2*)orow = make_float2(o0*inv, o1*inv);
  }
}

// K67: fused lepe+wo+LN+MLP. 32 px/block, grid 512, block 256.
// launch_bounds(256,2) frees VGPRs for pipelining; fc1/fc2 chunk-4.
__global__ void __launch_bounds__(256, 2)
k67_lepe_wo_mlp(const float* __restrict__ attnout,
                const float* __restrict__ qkv,
                const float* __restrict__ lw, const float* __restrict__ lb,
                const float* __restrict__ ww, const float* __restrict__ wb,
                const float* __restrict__ x1,
                const float* __restrict__ g, const float* __restrict__ bb,
                const float* __restrict__ w1, const float* __restrict__ b1,
                const float* __restrict__ w2, const float* __restrict__ b2,
                float* __restrict__ out){
  __shared__ __align__(16) float smem[13824];            // 55.3 KB
  float* x2T  = smem;                                    // [64][36]
  float* lnT  = smem + 2304;                             // [64][36]
  float* hidT = smem + 4608;                             // [256][36]
  float* tT   = hidT;                                    // alias (dead before D)
  float* red  = hidT;                                    // alias (after E)
  int tid = threadIdx.x, w = tid >> 6, lane = tid & 63;
  int pix0 = blockIdx.x * 32;

  // Phase A: lepe (lane = channel, 8 pixels per wave)
  float lwreg[25];
  #pragma unroll
  for (int t=0;t<25;t++) lwreg[t] = lw[lane*25 + t];
  float lbias = lb[lane];
  for (int i=0; i<8; i++){
    int pl = w*8 + i, pix = pix0 + pl;
    int y = pix >> 7, xx = pix & 127;
    float acc = lbias;
    #pragma unroll
    for (int dy=0; dy<5; dy++){
      int yy = y+dy-2; if ((unsigned)yy >= (unsigned)HPIX) continue;
      #pragma unroll
      for (int dx=0; dx<5; dx++){
        int x2c = xx+dx-2; if ((unsigned)x2c >= (unsigned)WPIX) continue;
        int pp = (yy>>3)*16 + (x2c>>3), rr = ((yy&7)<<3) + (x2c&7);
        acc += lwreg[dy*5 + dx] * qkv[(pp*HWIN + rr)*192 + 128 + lane];
      }
    }
    tT[lane*LNS + pl] = attnout[pix*CCH + lane] + acc;
  }
  __syncthreads();

  // Phase B: wo matmul (4 pix x 2 cols) + x1 residual -> x2T (LDS only)
  {
    int p0 = (tid & 7) * 4;
    int cg = tid >> 3;
    int j0 = cg * 2;
    float a0[4], a1[4];
    #pragma unroll
    for (int i=0;i<4;i++){ a0[i] = wb[j0]; a1[i] = wb[j0+1]; }
    #pragma unroll 4
    for (int k=0; k<64; k++){
      float4 a = *(const float4*)&tT[k*LNS + p0];
      float2 u = *(const float2*)(ww + k*64 + j0);
      a0[0]+=a.x*u.x; a1[0]+=a.x*u.y;
      a0[1]+=a.y*u.x; a1[1]+=a.y*u.y;
      a0[2]+=a.z*u.x; a1[2]+=a.z*u.y;
      a0[3]+=a.w*u.x; a1[3]+=a.w*u.y;
    }
    #pragma unroll
    for (int i=0;i<4;i++){
      int pix = pix0 + p0 + i;
      float2 r = *(const float2*)(x1 + pix*CCH + j0);
      x2T[j0*LNS + p0 + i]     = r.x + a0[i];
      x2T[(j0+1)*LNS + p0 + i] = r.y + a1[i];
    }
  }
  __syncthreads();

  // Phase C: LN from x2T
  #pragma unroll
  for (int i=0; i<8; i++){
    int pl = w*8 + i;
    float v = x2T[lane*LNS + pl];
    float mean = waveReduceSum(v) * (1.f/64.f);
    float d = v - mean;
    float var = waveReduceSum(d*d) * (1.f/64.f);
    lnT[lane*LNS + pl] = d * rsqrtf(var + 1e-6f) * g[lane] + bb[lane];
  }
  __syncthreads();

  // Phase D: fc1 + gelu (4 pix x 8 cols, chunk-4)
  {
    int p0 = (tid & 7) * 4;
    int j0 = (tid >> 3) * 8;
    float acc[4][8];
    #pragma unroll
    for (int i=0;i<4;i++)
      #pragma unroll
      for (int j=0;j<8;j++) acc[i][j] = b1[j0+j];
    for (int k0=0; k0<64; k0+=4){
      float4 a[4]; float4 u[4][2];
      #pragma unroll
      for (int t=0;t<4;t++){
        a[t] = *(const float4*)&lnT[(k0+t)*LNS + p0];
        const float* wr = w1 + (k0+t)*256 + j0;
        u[t][0] = *(const float4*)(wr);
        u[t][1] = *(const float4*)(wr+4);
      }
      #pragma unroll
      for (int t=0;t<4;t++){
        float av[4] = {a[t].x, a[t].y, a[t].z, a[t].w};
        #pragma unroll
        for (int i=0;i<4;i++){
          acc[i][0]+=av[i]*u[t][0].x; acc[i][1]+=av[i]*u[t][0].y;
          acc[i][2]+=av[i]*u[t][0].z; acc[i][3]+=av[i]*u[t][0].w;
          acc[i][4]+=av[i]*u[t][1].x; acc[i][5]+=av[i]*u[t][1].y;
          acc[i][6]+=av[i]*u[t][1].z; acc[i][7]+=av[i]*u[t][1].w;
        }
      }
    }
    #pragma unroll
    for (int j=0;j<8;j++){
      float4 hv;
      hv.x = gelu_exact(acc[0][j]);
      hv.y = gelu_exact(acc[1][j]);
      hv.z = gelu_exact(acc[2][j]);
      hv.w = gelu_exact(acc[3][j]);
      *(float4*)&hidT[(j0+j)*LNS + p0] = hv;
    }
  }
  __syncthreads();

  // Phase E: fc2 K-split across 4 waves (4 pix x 8 cols, chunk-4)
  float acc2[4][8];
  {
    int p0 = (lane & 7) * 4;
    int c0 = (lane >> 3) * 8;
    #pragma unroll
    for (int i=0;i<4;i++)
      #pragma unroll
      for (int j=0;j<8;j++) acc2[i][j] = 0.f;
    int kbase = w*64;
    for (int k0=0; k0<64; k0+=4){
      float4 a[4]; float4 u[4][2];
      #pragma unroll
      for (int t=0;t<4;t++){
        int k = kbase + k0 + t;
        a[t] = *(const float4*)&hidT[k*LNS + p0];
        const float* wr = w2 + k*64 + c0;
        u[t][0] = *(const float4*)(wr);
        u[t][1] = *(const float4*)(wr+4);
      }
      #pragma unroll
      for (int t=0;t<4;t++){
        float av[4] = {a[t].x, a[t].y, a[t].z, a[t].w};
        #pragma unroll
        for (int i=0;i<4;i++){
          acc2[i][0]+=av[i]*u[t][0].x; acc2[i][1]+=av[i]*u[t][0].y;
          acc2[i][2]+=av[i]*u[t][0].z; acc2[i][3]+=av[i]*u[t][0].w;
          acc2[i][4]+=av[i]*u[t][1].x; acc2[i][5]+=av[i]*u[t][1].y;
          acc2[i][6]+=av[i]*u[t][1].z; acc2[i][7]+=av[i]*u[t][1].w;
        }
      }
    }
  }
  __syncthreads();   // hidT dead; overlay red
  #pragma unroll
  for (int t=0; t<16; t++){
    int s = 2*t, i = s >> 3, j = s & 7;
    *(float2*)&red[tid*34 + s] = make_float2(acc2[i][j], acc2[i][j+1]);
  }
  __syncthreads();

  // Phase F: reduce partials + bias + residual (from x2T) + NCHW store
  {
    int lane_r = tid & 63, ir = tid >> 6;
    int pg = lane_r & 7, cgf = lane_r >> 3;
    int pix = pix0 + pg*4 + ir;
    int c0 = cgf*8;
    float o[8];
    #pragma unroll
    for (int j=0;j<8;j++) o[j] = b2[c0+j];
    #pragma unroll
    for (int wq=0; wq<4; wq++){
      const float* rp = &red[(wq*64 + lane_r)*34 + ir*8];
      #pragma unroll
      for (int j2=0;j2<4;j2++){
        float2 pr = *(const float2*)(rp + 2*j2);
        o[2*j2]   += pr.x;
        o[2*j2+1] += pr.y;
      }
    }
    int plocal = pg*4 + ir;
    #pragma unroll
    for (int j=0;j<8;j++)
      o[j] += x2T[(c0+j)*LNS + plocal];
    #pragma unroll
    for (int j=0;j<8;j++)
      out[(c0+j)*NPIX + pix] = o[j];
  }
}

extern "C" void kernel_launch(void* const* d_in, const int* in_sizes, int n_in,
                              void* d_out, int out_size, void* d_ws, size_t ws_size,
                              hipStream_t stream) {
  (void)in_sizes; (void)n_in; (void)out_size; (void)ws_size;
  const float* x      = (const float*)d_in[0];
  const float* pos_w  = (const float*)d_in[1];
  const float* pos_b  = (const float*)d_in[2];
  const float* norm_g = (const float*)d_in[3];
  const float* norm_b = (const float*)d_in[4];
  const float* qkv_w  = (const float*)d_in[5];
  const float* qkv_b  = (const float*)d_in[6];
  const float* wo_w   = (const float*)d_in[7];
  const float* wo_b   = (const float*)d_in[8];
  const float* lepe_w = (const float*)d_in[9];
  const float* lepe_b = (const float*)d_in[10];
  const float* mlp_w1 = (const float*)d_in[11];
  const float* mlp_b1 = (const float*)d_in[12];
  const float* mlp_w2 = (const float*)d_in[13];
  const float* mlp_b2 = (const float*)d_in[14];
  float* out = (float*)d_out;

  char* ws = (char*)d_ws;
  float* x1      = (float*)(ws);                          // 4 MB
  float* qkv     = (float*)(ws + (4u<<20));               // 12 MB [p][r][192]
  float* qwin    = (float*)(ws + (16u<<20));              // 64 KB
  float* kwinT   = (float*)(ws + (16u<<20) + (64u<<10));  // 64 KB  [c][p]
  int*   idx     = (int*)  (ws + (16u<<20) + (128u<<10)); // 4 KB
  float* attnout = (float*)(ws + (17u<<20));              // 4 MB (NHWC)

  hipLaunchKernelGGL(k1_posconv,      dim3(4096), dim3(256), 0, stream, x, pos_w, pos_b, x1);
  hipLaunchKernelGGL(k2_ln_qkv,       dim3(512),  dim3(256), 0, stream, x1, norm_g, norm_b, qkv_w, qkv_b, qkv);
  hipLaunchKernelGGL(k3_winmean,      dim3(256),  dim3(256), 0, stream, qkv, qwin, kwinT);
  hipLaunchKernelGGL(k4_topk,         dim3(256),  dim3(256), 0, stream, qwin, kwinT, idx);
  hipLaunchKernelGGL(k5_attn,         dim3(2048), dim3(256), 0, stream, qkv, idx, attnout);
  hipLaunchKernelGGL(k67_lepe_wo_mlp, dim3(512),  dim3(256), 0, stream, attnout, qkv,
                     lepe_w, lepe_b, wo_w, wo_b, x1, norm_g, norm_b,
                     mlp_w1, mlp_b1, mlp_w2, mlp_b2, out);
}